// Round 19
// baseline (759.753 us; speedup 1.0000x reference)
//
#include <hip/hip_runtime.h>
#include <math.h>

#define KK 20
#define NPTS 1024
#define BB 8
#define EPSF 1e-5f

// ====================== KNN selection (fp32, all-VALU reduce) ===========
// Verified R14/R15/R18: lexicographic argmax-merge, coverage-complete DPP
// tree, zero LDS ops. In-row: xor1, xor2, ror4, ror8; cross-row:
// row_bcast15, row_bcast31 -> lane 63 global winner; readlane broadcasts.
__device__ __forceinline__ void kmerge(float& bd, int& bi, float od, int oi) {
  if (od > bd || (od == bd && oi < bi)) { bd = od; bi = oi; }
}

template <int CTRL>
__device__ __forceinline__ void dpp_step(float& bd, int& bi) {
  int vd = __builtin_amdgcn_update_dpp(0, __float_as_int(bd), CTRL, 0xF, 0xF, true);
  int vi = __builtin_amdgcn_update_dpp(0, bi, CTRL, 0xF, 0xF, true);
  kmerge(bd, bi, __int_as_float(vd), vi);
}

__device__ __forceinline__ void select20f(float (&d)[16], int lane, int* orow)
{
  int keep = 0;
  for (int s = 0; s < KK; ++s) {
    float bd = d[0]; int bj = 0;
    #pragma unroll
    for (int j = 1; j < 16; ++j)
      if (d[j] > bd) { bd = d[j]; bj = j; }
    int bi = bj * 64 + lane;

    dpp_step<0xB1>(bd, bi);              // quad_perm xor1
    dpp_step<0x4E>(bd, bi);              // quad_perm xor2
    dpp_step<0x124>(bd, bi);             // row_ror:4
    dpp_step<0x128>(bd, bi);             // row_ror:8
    dpp_step<0x142>(bd, bi);             // row_bcast15
    dpp_step<0x143>(bd, bi);             // row_bcast31 -> lane63 global
    const int wbi = __builtin_amdgcn_readlane(bi, 63);

    if (lane == s) keep = wbi;
    if ((wbi & 63) == lane) {
      int jw = wbi >> 6;
      #pragma unroll
      for (int j = 0; j < 16; ++j)
        if (j == jw) d[j] = -INFINITY;
    }
  }
  if (lane < KK) orow[lane] = keep;
}

// ==== KNN v14: 4 pts/wave, 256-thr blocks, quad-b128, DPP select ========
// R18 lesson: knn is LDS-TRAFFIC-bound (occupancy 2x in v13 was neutral).
// v14 halves dot-phase traffic again: each strided b128 feeds 16 fma
// (4 points share every m-column read). Select is all-VALU (verified) so
// the v9 failure mode (LDS-shuffle select) is gone. VGPR ~114 < 256 cap
// of launch_bounds(256,2): no spill. 256 thr = 4 waves = 16 pts/block,
// grid (64,8) = 512 blocks = 2 blocks/CU. Staging = knn13's verified
// pattern (each thread 4 m: 2t, 2t+1, 512+2t, 512+2t+1). Per-point fma
// chains (xx, dot, ascending c) bitwise identical to verified knn12/13;
// self column (2X-X)-X == 0 exactly.
template <int C, int CEFF>
__global__ __launch_bounds__(256, 2) void knn14_kernel(
    const float* __restrict__ x, long bstride,
    int* __restrict__ idx_out)
{
  const int t = threadIdx.x, w = t >> 6, lane = t & 63;
  const int b = blockIdx.y;
  const int n0 = blockIdx.x * 16;
  const int p0 = n0 + 4 * w;          // this wave's 4 points p0..p0+3
  __shared__ float xs4[NPTS * 4];     // [m*4 + c], 16 KB
  __shared__ float xxs[NPTS];         // 4 KB
  const float* xb = x + (long)b * bstride;

  // r2[2j+h]: channel c0+j, half h -> cols (512h + 2t, +1)
  float2 r2[8];
  #pragma unroll
  for (int j = 0; j < 4; ++j) {
    if (j < CEFF) {
      r2[2 * j]     = *(const float2*)&xb[(long)j * NPTS + 2 * t];
      r2[2 * j + 1] = *(const float2*)&xb[(long)j * NPTS + 512 + 2 * t];
    } else {
      r2[2 * j] = make_float2(0.f, 0.f);
      r2[2 * j + 1] = make_float2(0.f, 0.f);
    }
  }

  float xx0 = 0.f, xx1 = 0.f;         // m = 2t, 2t+1
  float xx2 = 0.f, xx3 = 0.f;         // m = 512+2t, 512+2t+1
  float dot[4][16];
  #pragma unroll
  for (int q = 0; q < 4; ++q)
    #pragma unroll
    for (int j = 0; j < 16; ++j) dot[q][j] = 0.f;

  for (int c0 = 0; c0 < C; c0 += 4) {
    __syncthreads();                  // prev compute done reading xs4
    {
      float4 w0 = make_float4(r2[0].x, r2[2].x, r2[4].x, r2[6].x);
      float4 w1 = make_float4(r2[0].y, r2[2].y, r2[4].y, r2[6].y);
      float4 w2 = make_float4(r2[1].x, r2[3].x, r2[5].x, r2[7].x);
      float4 w3 = make_float4(r2[1].y, r2[3].y, r2[5].y, r2[7].y);
      *(float4*)&xs4[(2 * t) * 4]           = w0;   // m=2t
      *(float4*)&xs4[(2 * t + 1) * 4]       = w1;   // m=2t+1
      *(float4*)&xs4[(512 + 2 * t) * 4]     = w2;   // m=512+2t
      *(float4*)&xs4[(512 + 2 * t + 1) * 4] = w3;   // m=512+2t+1
    }
    #pragma unroll
    for (int j = 0; j < 4; ++j) {     // xx from own regs, ascending c
      xx0 = fmaf(r2[2 * j].x,     r2[2 * j].x,     xx0);
      xx1 = fmaf(r2[2 * j].y,     r2[2 * j].y,     xx1);
      xx2 = fmaf(r2[2 * j + 1].x, r2[2 * j + 1].x, xx2);
      xx3 = fmaf(r2[2 * j + 1].y, r2[2 * j + 1].y, xx3);
    }
    __syncthreads();
    if (c0 + 4 < C) {                 // prefetch next chunk (overlaps compute)
      #pragma unroll
      for (int j = 0; j < 4; ++j) {
        r2[2 * j]     = *(const float2*)&xb[(long)(c0 + 4 + j) * NPTS + 2 * t];
        r2[2 * j + 1] = *(const float2*)&xb[(long)(c0 + 4 + j) * NPTS + 512 + 2 * t];
      }
    }
    {
      float4 cp[4];
      #pragma unroll
      for (int q = 0; q < 4; ++q)     // wave-uniform broadcasts
        cp[q] = *(const float4*)&xs4[(p0 + q) * 4];
      #pragma unroll
      for (int j = 0; j < 16; ++j) {
        float4 v = *(const float4*)&xs4[(j * 64 + lane) * 4];
        #pragma unroll
        for (int q = 0; q < 4; ++q) { // each strided b128 feeds 16 fma
          dot[q][j] = fmaf(cp[q].x, v.x, dot[q][j]);   // ascending c in quad
          dot[q][j] = fmaf(cp[q].y, v.y, dot[q][j]);
          dot[q][j] = fmaf(cp[q].z, v.z, dot[q][j]);
          dot[q][j] = fmaf(cp[q].w, v.w, dot[q][j]);
        }
      }
    }
  }
  *(float2*)&xxs[2 * t]       = make_float2(xx0, xx1);
  *(float2*)&xxs[512 + 2 * t] = make_float2(xx2, xx3);
  __syncthreads();

  #pragma unroll
  for (int q = 0; q < 4; ++q) {       // in-place; m==p: (2X-X)-X == 0 exact
    const float xxP = xxs[p0 + q];
    #pragma unroll
    for (int j = 0; j < 16; ++j) {
      float xm = xxs[j * 64 + lane];
      dot[q][j] = (2.0f * dot[q][j] - xxP) - xm;
    }
  }
  #pragma unroll
  for (int q = 0; q < 4; ++q)
    select20f(dot[q], lane, idx_out + ((long)b * NPTS + p0 + q) * KK);
}

// ========== dual GEMV: Yc[b][n][o] = sum_c (w2-w1)*x,  G[b][m][o] = sum_c w1*x
template <typename AccT, int C, int O, int CB2, int TN>
__global__ __launch_bounds__(256) void cg_kernel(
    const float* __restrict__ x, long bstride,
    const float* __restrict__ W,
    AccT* __restrict__ Yc,
    AccT* __restrict__ G, long gbs)
{
  const int t = threadIdx.x, b = blockIdx.y;
  const int o = t & (O - 1);
  const int nbase = (t / O) * 16;
  const int nn0 = blockIdx.x * TN;
  __shared__ float s_wd[CB2 * O];
  __shared__ float s_w1[CB2 * O];
  __shared__ float s_xs[CB2 * TN];
  const float* xb = x + (long)b * bstride;

  AccT accC[16], accG[16];
  #pragma unroll
  for (int j = 0; j < 16; ++j) { accC[j] = (AccT)0; accG[j] = (AccT)0; }

  for (int c0 = 0; c0 < C; c0 += CB2) {
    __syncthreads();
    for (int i = t; i < CB2 * O; i += 256) {
      int oo = i / CB2, cc = i - oo * CB2;
      float a  = W[(long)oo * (2 * C) + c0 + cc];
      float b2 = W[(long)oo * (2 * C) + C + c0 + cc];
      s_wd[cc * O + oo] = b2 - a;
      s_w1[cc * O + oo] = a;
    }
    for (int i = t; i < CB2 * TN; i += 256) {
      int cc = i / TN, nn = i - cc * TN;
      s_xs[cc * TN + nn] = xb[(long)(c0 + cc) * NPTS + nn0 + nn];
    }
    __syncthreads();
    #pragma unroll
    for (int cc = 0; cc < CB2; ++cc) {
      float wd  = s_wd[cc * O + o];
      float w1v = s_w1[cc * O + o];
      #pragma unroll
      for (int j = 0; j < 16; ++j) {
        AccT xv = (AccT)s_xs[cc * TN + nbase + j];
        accC[j] += (AccT)wd  * xv;
        accG[j] += (AccT)w1v * xv;
      }
    }
  }
  #pragma unroll
  for (int j = 0; j < 16; ++j) {
    int n = nn0 + nbase + j;
    Yc[((long)b * NPTS + n) * O + o] = accC[j];
    G[(long)b * gbs + (long)n * O + o] = accG[j];
  }
}

// ============ EdgeConv epilogue: gather G rows, max/sum/sumsq over k ====
template <typename AccT, int O, int NPT, int ITERS>
__global__ __launch_bounds__(256) void ec_max_kernel(
    const int* __restrict__ idx,
    const AccT* __restrict__ G, long gbs,
    const AccT* __restrict__ Yc,
    double* __restrict__ sums,
    AccT* __restrict__ yraw)
{
  const int t = threadIdx.x, b = blockIdx.y;
  const int o = t & (O - 1);
  const int np = t / O;
  const int LP = NPT * ITERS;
  const int n0 = blockIdx.x * LP;

  __shared__ int s_jj[8 * KK];          // LP <= 8
  __shared__ double reds[256];
  __shared__ double redq[256];

  for (int i = t; i < LP * KK; i += 256) {
    int l = i / KK, kk = i - l * KK;
    s_jj[i] = idx[((long)b * NPTS + n0 + l) * KK + kk];
  }
  __syncthreads();

  const AccT* Gb = G + (long)b * gbs + o;
  double accS = 0.0, accQ = 0.0;
  #pragma unroll
  for (int it = 0; it < ITERS; ++it) {
    const int l = it * NPT + np;
    const int n = n0 + l;
    AccT y0 = Yc[((long)b * NPTS + n) * O + o];
    AccT ps = (AccT)0, pq = (AccT)0, pm = (AccT)(-INFINITY);
    #pragma unroll
    for (int k = 0; k < KK; ++k) {
      int j = s_jj[l * KK + k];          // wave-uniform (LDS broadcast)
      AccT v = Gb[(long)j * O] + y0;     // coalesced over o
      ps += v; pq += v * v;
      pm = (v > pm) ? v : pm;
    }
    yraw[((long)b * NPTS + n) * O + o] = pm;
    accS += (double)ps; accQ += (double)pq;
  }
  __syncthreads();
  reds[t] = accS; redq[t] = accQ;
  __syncthreads();
  if (t < O) {
    double s = 0.0, q = 0.0;
    #pragma unroll
    for (int g = 0; g < NPT; ++g) { s += reds[g * O + t]; q += redq[g * O + t]; }
    atomicAdd(&sums[t], s);
    atomicAdd(&sums[1024 + t], q);
  }
}

// normalize + lrelu the raw k-max, write into cat layout [b][o][n]
template <typename AccT, int O, int OL>
__global__ __launch_bounds__(256) void ec_norm(
    const AccT* __restrict__ yraw, const double* __restrict__ sums,
    const float* __restrict__ gamma, const float* __restrict__ beta,
    float* __restrict__ xout)
{
  int i = blockIdx.x * 256 + threadIdx.x;
  int n = i & (NPTS - 1);
  int o = (i >> 10) & (O - 1);
  int b = i >> (10 + OL);
  const double cnt = (double)BB * NPTS * KK;
  double m = sums[o] / cnt;
  double var = sums[1024 + o] / cnt - m * m;
  double inv = 1.0 / sqrt(var + (double)EPSF);
  AccT y = yraw[((long)b * NPTS + n) * O + o];
  AccT v = (y - (AccT)m) * (AccT)inv * (AccT)gamma[o] + (AccT)beta[o];
  v = (v >= (AccT)0) ? v : (AccT)0.2 * v;
  xout[(long)b * (512L * NPTS) + (long)o * NPTS + n] = (float)v;
}

// ============== Final 512->1024 conv, fused single pass =================
// v5 (R16/R18, best measured): 256 o x 64 n, acc[4][16], grid (128,4),
// no atomics -- block partials to workspace, fin_reduce fixed order.
#define WST2 260

__global__ __launch_bounds__(256, 2) void fin_fused(
    const float* __restrict__ cat, const float* __restrict__ W5,
    double* __restrict__ partS, float* __restrict__ partM)
{
  const int nt = blockIdx.x, ot = blockIdx.y, t = threadIdx.x;
  const int w = t >> 6, lane = t & 63;
  const int col0 = nt * 64;
  const int b = col0 >> 10;
  const int nb = col0 & 1023;

  __shared__ float sm[16 * WST2 + 16 * 64];   // 20.7 KB
  float* s_w = sm;             // [16][WST2]  (cc-major, +4 pad)
  float* s_f = sm + 16 * WST2; // [16][64]

  const int wrow0 = t >> 2, wcq = (t & 3) * 4;
  const float* wbase = W5 + ((long)(ot * 256 + wrow0)) * 512 + wcq;
  const int fcc = t >> 4, fnn = (t & 15) * 4;
  const float* fbase = cat + ((long)b * 512 + fcc) * 1024 + nb + fnn;

  float4 rw[4];
  float4 rf;
  #pragma unroll
  for (int q = 0; q < 4; ++q)
    rw[q] = *(const float4*)&wbase[(long)(64 * q) * 512];
  rf = *(const float4*)fbase;

  float acc[4][16];
  #pragma unroll
  for (int r = 0; r < 4; ++r)
    #pragma unroll
    for (int j = 0; j < 16; ++j) acc[r][j] = 0.f;

  for (int c0 = 0; c0 < 512; c0 += 16) {
    __syncthreads();                 // previous compute done reading LDS
    #pragma unroll
    for (int q = 0; q < 4; ++q) {
      float e[4] = {rw[q].x, rw[q].y, rw[q].z, rw[q].w};
      #pragma unroll
      for (int j = 0; j < 4; ++j)
        s_w[(wcq + j) * WST2 + wrow0 + 64 * q] = e[j];
    }
    *(float4*)&s_f[fcc * 64 + fnn] = rf;
    __syncthreads();
    if (c0 + 16 < 512) {             // prefetch next chunk -> overlaps compute
      #pragma unroll
      for (int q = 0; q < 4; ++q)
        rw[q] = *(const float4*)&wbase[(long)(64 * q) * 512 + c0 + 16];
      rf = *(const float4*)&fbase[(long)(c0 + 16) * 1024];
    }
    #pragma unroll
    for (int cc = 0; cc < 16; ++cc) {
      float4 wA = *(const float4*)&s_w[cc * WST2 + lane * 4];   // conflict-free
      float4 f0 = *(const float4*)&s_f[cc * 64 + w * 16];       // wave-uniform
      float4 f1 = *(const float4*)&s_f[cc * 64 + w * 16 + 4];   // broadcasts
      float4 f2 = *(const float4*)&s_f[cc * 64 + w * 16 + 8];
      float4 f3 = *(const float4*)&s_f[cc * 64 + w * 16 + 12];
      float wa[4] = {wA.x, wA.y, wA.z, wA.w};
      float fv[16] = {f0.x, f0.y, f0.z, f0.w, f1.x, f1.y, f1.z, f1.w,
                      f2.x, f2.y, f2.z, f2.w, f3.x, f3.y, f3.z, f3.w};
      #pragma unroll
      for (int r = 0; r < 4; ++r)
        #pragma unroll
        for (int j = 0; j < 16; ++j)
          acc[r][j] += wa[r] * fv[j];
    }
  }

  float psum[4], psq[4], pmx[4];
  #pragma unroll
  for (int r = 0; r < 4; ++r) {
    psum[r] = 0.f; psq[r] = 0.f; pmx[r] = -INFINITY;
    #pragma unroll
    for (int j = 0; j < 16; ++j) {
      float v = acc[r][j];
      psum[r] += v; psq[r] += v * v; pmx[r] = fmaxf(pmx[r], v);
    }
  }
  __syncthreads();
  float* red_s = sm;           // [4][256]
  float* red_q = sm + 1024;
  float* red_m = sm + 2048;
  #pragma unroll
  for (int r = 0; r < 4; ++r) {
    int oo = lane * 4 + r;
    red_s[w * 256 + oo] = psum[r];
    red_q[w * 256 + oo] = psq[r];
    red_m[w * 256 + oo] = pmx[r];
  }
  __syncthreads();
  {
    int oo = t;                // 0..255
    float s = 0.f, q = 0.f, m = -INFINITY;
    #pragma unroll
    for (int ww = 0; ww < 4; ++ww) {
      s += red_s[ww * 256 + oo];
      q += red_q[ww * 256 + oo];
      m = fmaxf(m, red_m[ww * 256 + oo]);
    }
    long base = (long)nt * 2048 + ot * 256 + oo;   // o = ot*256+oo
    partS[base]        = (double)s;                // coalesced, no atomics
    partS[base + 1024] = (double)q;
    partM[(long)nt * 1024 + ot * 256 + oo] = m;
  }
}

// sum the 128 nt-partials per (o, kind) slot in fixed ascending order
__global__ __launch_bounds__(256) void fin_reduce(
    const double* __restrict__ partS, double* __restrict__ sums)
{
  int slot = blockIdx.x * 256 + threadIdx.x;   // 0..2047
  double a = 0.0;
  for (int nt = 0; nt < 128; ++nt)
    a += partS[(long)nt * 2048 + slot];
  sums[slot] = a;
}

__global__ __launch_bounds__(256) void fin_norm(
    const float* __restrict__ partM, const double* __restrict__ sums,
    const float* __restrict__ g, const float* __restrict__ bt,
    float* __restrict__ out)
{
  int i = blockIdx.x * 256 + threadIdx.x;   // 8192
  int o = i & 1023;
  int b = i >> 10;
  double m = sums[o] / 8192.0;
  double var = sums[1024 + o] / 8192.0 - m * m;
  float inv = (float)(1.0 / sqrt(var + (double)EPSF));
  float y = -INFINITY;
  #pragma unroll 4
  for (int j = 0; j < 16; ++j)
    y = fmaxf(y, partM[(long)(b * 16 + j) * 1024 + o]);
  float v = (y - (float)m) * inv * g[o] + bt[o];
  out[i] = (v >= 0.f) ? v : 0.2f * v;
}

// ============================ launch ====================================
extern "C" void kernel_launch(void* const* d_in, const int* in_sizes, int n_in,
                              void* d_out, int out_size, void* d_ws, size_t ws_size,
                              hipStream_t stream)
{
  (void)in_sizes; (void)n_in; (void)out_size; (void)ws_size;
  const float* x0 = (const float*)d_in[0];
  const float* W1 = (const float*)d_in[1];
  const float* g1 = (const float*)d_in[2];
  const float* b1 = (const float*)d_in[3];
  const float* W2 = (const float*)d_in[4];
  const float* g2 = (const float*)d_in[5];
  const float* b2 = (const float*)d_in[6];
  const float* W3 = (const float*)d_in[7];
  const float* g3 = (const float*)d_in[8];
  const float* b3 = (const float*)d_in[9];
  const float* W4 = (const float*)d_in[10];
  const float* g4 = (const float*)d_in[11];
  const float* b4 = (const float*)d_in[12];
  const float* W5 = (const float*)d_in[13];
  const float* g5 = (const float*)d_in[14];
  const float* b5 = (const float*)d_in[15];
  float* outp = (float*)d_out;

  char* w = (char*)d_ws;
  double*   sums   = (double*)w;   w += 5 * 2048 * sizeof(double);            // 80 KB
  unsigned* mkeys  = (unsigned*)w; w += (size_t)BB * 1024 * sizeof(unsigned); // 32 KB (unused, layout kept)
  int*      idxbuf = (int*)w;      w += (size_t)BB * NPTS * KK * sizeof(int); // 640 KB
  char*     yraw   = w;            w += (size_t)BB * NPTS * 128 * sizeof(double); // 8 MB
  char*     ycbuf  = w;            w += (size_t)BB * NPTS * 128 * sizeof(double); // 8 MB
  float*    cat    = (float*)w;    // 16 MB

  double* sumsL[5] = {sums, sums + 2048, sums + 4096, sums + 6144, sums + 8192};

  const long catbs = 512L * NPTS;
  // G lives in the cat[256:512) slab per batch (1 MB/batch), which is only
  // written by layer-4's ec_norm -- strictly after every G consumer.
  float* gbase = cat + 256 * NPTS;
  // fin partials reuse yraw (dead after layer-4 ec_norm): 2 MB f64 + 0.5 MB f32
  double* partS = (double*)yraw;
  float*  partM = (float*)(yraw + (size_t)128 * 2048 * sizeof(double));

  dim3 gknn(NPTS / 16, BB);

  hipMemsetAsync(sums, 0, 5 * 2048 * sizeof(double) + (size_t)BB * 1024 * sizeof(unsigned),
                 stream);

  // ---- layer 1: x0 (C=3) -> cat[0:64), fp64 acc ----
  knn14_kernel<4, 3><<<gknn, 256, 0, stream>>>(x0, 3L * NPTS, idxbuf);
  cg_kernel<double, 3, 64, 3, 64><<<dim3(NPTS / 64, BB), 256, 0, stream>>>(
      x0, 3L * NPTS, W1, (double*)ycbuf, (double*)gbase, catbs / 2);
  ec_max_kernel<double, 64, 4, 2><<<dim3(NPTS / 8, BB), 256, 0, stream>>>(
      idxbuf, (const double*)gbase, catbs / 2, (const double*)ycbuf,
      sumsL[0], (double*)yraw);
  ec_norm<double, 64, 6><<<BB * 64 * NPTS / 256, 256, 0, stream>>>(
      (const double*)yraw, sumsL[0], g1, b1, cat);

  // ---- layer 2: cat[0:64) -> cat[64:128), fp64 acc ----
  knn14_kernel<64, 64><<<gknn, 256, 0, stream>>>(cat, catbs, idxbuf);
  cg_kernel<double, 64, 64, 16, 64><<<dim3(NPTS / 64, BB), 256, 0, stream>>>(
      cat, catbs, W2, (double*)ycbuf, (double*)gbase, catbs / 2);
  ec_max_kernel<double, 64, 4, 2><<<dim3(NPTS / 8, BB), 256, 0, stream>>>(
      idxbuf, (const double*)gbase, catbs / 2, (const double*)ycbuf,
      sumsL[1], (double*)yraw);
  ec_norm<double, 64, 6><<<BB * 64 * NPTS / 256, 256, 0, stream>>>(
      (const double*)yraw, sumsL[1], g2, b2, cat + 64 * NPTS);

  // ---- layer 3: cat[64:128) -> cat[128:256), fp64 acc ----
  knn14_kernel<64, 64><<<gknn, 256, 0, stream>>>(cat + 64 * NPTS, catbs, idxbuf);
  cg_kernel<double, 64, 128, 16, 32><<<dim3(NPTS / 32, BB), 256, 0, stream>>>(
      cat + 64 * NPTS, catbs, W3, (double*)ycbuf, (double*)gbase, catbs / 2);
  ec_max_kernel<double, 128, 2, 4><<<dim3(NPTS / 8, BB), 256, 0, stream>>>(
      idxbuf, (const double*)gbase, catbs / 2, (const double*)ycbuf,
      sumsL[2], (double*)yraw);
  ec_norm<double, 128, 7><<<BB * 128 * NPTS / 256, 256, 0, stream>>>(
      (const double*)yraw, sumsL[2], g3, b3, cat + 128 * NPTS);

  // ---- layer 4: cat[128:256) -> cat[256:512), fp32 acc (continuous path) ----
  knn14_kernel<128, 128><<<gknn, 256, 0, stream>>>(cat + 128 * NPTS, catbs, idxbuf);
  cg_kernel<float, 128, 256, 16, 16><<<dim3(NPTS / 16, BB), 256, 0, stream>>>(
      cat + 128 * NPTS, catbs, W4, (float*)ycbuf, gbase, catbs);
  ec_max_kernel<float, 256, 1, 4><<<dim3(NPTS / 4, BB), 256, 0, stream>>>(
      idxbuf, (const float*)gbase, catbs, (const float*)ycbuf,
      sumsL[3], (float*)yraw);
  ec_norm<float, 256, 8><<<BB * 256 * NPTS / 256, 256, 0, stream>>>(
      (const float*)yraw, sumsL[3], g4, b4, cat + 256 * NPTS);

  // ---- final 512->1024 conv + BN + lrelu + max over n (no atomics) ----
  dim3 gf(128, 4);
  fin_fused<<<gf, 256, 0, stream>>>(cat, W5, partS, partM);
  fin_reduce<<<8, 256, 0, stream>>>(partS, sumsL[4]);
  fin_norm<<<BB * 1024 / 256, 256, 0, stream>>>(partM, sumsL[4], g5, b5, outp);
}

// Round 20
// 701.799 us; speedup vs baseline: 1.0826x; 1.0826x over previous
//
#include <hip/hip_runtime.h>
#include <math.h>

#define KK 20
#define NPTS 1024
#define BB 8
#define EPSF 1e-5f

// ====================== KNN selection (fp32, all-VALU reduce) ===========
// Verified R14/R15/R16: lexicographic argmax-merge, coverage-complete DPP
// tree, zero LDS ops. In-row: xor1, xor2, ror4, ror8; cross-row:
// row_bcast15, row_bcast31 -> lane 63 global winner; readlane broadcasts.
__device__ __forceinline__ void kmerge(float& bd, int& bi, float od, int oi) {
  if (od > bd || (od == bd && oi < bi)) { bd = od; bi = oi; }
}

template <int CTRL>
__device__ __forceinline__ void dpp_step(float& bd, int& bi) {
  int vd = __builtin_amdgcn_update_dpp(0, __float_as_int(bd), CTRL, 0xF, 0xF, true);
  int vi = __builtin_amdgcn_update_dpp(0, bi, CTRL, 0xF, 0xF, true);
  kmerge(bd, bi, __int_as_float(vd), vi);
}

__device__ __forceinline__ void select20f(float (&d)[16], int lane, int* orow)
{
  int keep = 0;
  for (int s = 0; s < KK; ++s) {
    float bd = d[0]; int bj = 0;
    #pragma unroll
    for (int j = 1; j < 16; ++j)
      if (d[j] > bd) { bd = d[j]; bj = j; }
    int bi = bj * 64 + lane;

    dpp_step<0xB1>(bd, bi);              // quad_perm xor1
    dpp_step<0x4E>(bd, bi);              // quad_perm xor2
    dpp_step<0x124>(bd, bi);             // row_ror:4
    dpp_step<0x128>(bd, bi);             // row_ror:8
    dpp_step<0x142>(bd, bi);             // row_bcast15
    dpp_step<0x143>(bd, bi);             // row_bcast31 -> lane63 global
    const int wbi = __builtin_amdgcn_readlane(bi, 63);

    if (lane == s) keep = wbi;
    if ((wbi & 63) == lane) {
      int jw = wbi >> 6;
      #pragma unroll
      for (int j = 0; j < 16; ++j)
        if (j == jw) d[j] = -INFINITY;
    }
  }
  if (lane < KK) orow[lane] = keep;
}

// ==== KNN v12 (R15/R16, best measured): fp32, 2 pts/wave, quad-b128 =====
// Design-space mapping: 1 pt/wave (R15: neutral-worse), occupancy 2x
// (R18: neutral), 4 pts/wave (R19: regression -- serial selects at low
// occupancy). v12 is the measured balance point.
template <int C, int CEFF>
__global__ __launch_bounds__(512, 4) void knn12_kernel(
    const float* __restrict__ x, long bstride,
    int* __restrict__ idx_out)
{
  const int t = threadIdx.x, w = t >> 6, lane = t & 63;
  const int b = blockIdx.y;
  const int n0 = blockIdx.x * 16;
  const int pa = n0 + 2 * w, pb = pa + 1;
  __shared__ float xs4[NPTS * 4];     // [m*4 + c], 16 KB
  __shared__ float xxs[NPTS];         // 4 KB
  const float* xb = x + (long)b * bstride;

  float2 r2[4];
  #pragma unroll
  for (int j = 0; j < 4; ++j) {
    if (j < CEFF) r2[j] = *(const float2*)&xb[(long)j * NPTS + 2 * t];
    else          r2[j] = make_float2(0.f, 0.f);
  }

  float xx0 = 0.f, xx1 = 0.f;         // m = 2t, 2t+1
  float dotA[16], dotB[16];
  #pragma unroll
  for (int j = 0; j < 16; ++j) { dotA[j] = 0.f; dotB[j] = 0.f; }

  for (int c0 = 0; c0 < C; c0 += 4) {
    __syncthreads();                  // prev compute done reading xs4
    {
      float4 w0 = make_float4(r2[0].x, r2[1].x, r2[2].x, r2[3].x);
      float4 w1 = make_float4(r2[0].y, r2[1].y, r2[2].y, r2[3].y);
      *(float4*)&xs4[(2 * t) * 4]     = w0;   // m=2t,   c0..c3
      *(float4*)&xs4[(2 * t + 1) * 4] = w1;   // m=2t+1, c0..c3
    }
    #pragma unroll
    for (int j = 0; j < 4; ++j) {     // xx from own regs, ascending c
      xx0 = fmaf(r2[j].x, r2[j].x, xx0);
      xx1 = fmaf(r2[j].y, r2[j].y, xx1);
    }
    __syncthreads();
    if (c0 + 4 < C) {                 // prefetch next chunk (overlaps compute)
      #pragma unroll
      for (int j = 0; j < 4; ++j)
        r2[j] = *(const float2*)&xb[(long)(c0 + 4 + j) * NPTS + 2 * t];
    }
    {
      float4 ca = *(const float4*)&xs4[pa * 4];   // wave-uniform broadcasts
      float4 cb = *(const float4*)&xs4[pb * 4];
      #pragma unroll
      for (int j = 0; j < 16; ++j) {
        float4 v = *(const float4*)&xs4[(j * 64 + lane) * 4];
        dotA[j] = fmaf(ca.x, v.x, dotA[j]);       // ascending c in quad
        dotA[j] = fmaf(ca.y, v.y, dotA[j]);
        dotA[j] = fmaf(ca.z, v.z, dotA[j]);
        dotA[j] = fmaf(ca.w, v.w, dotA[j]);
        dotB[j] = fmaf(cb.x, v.x, dotB[j]);
        dotB[j] = fmaf(cb.y, v.y, dotB[j]);
        dotB[j] = fmaf(cb.z, v.z, dotB[j]);
        dotB[j] = fmaf(cb.w, v.w, dotB[j]);
      }
    }
  }
  *(float2*)&xxs[2 * t] = make_float2(xx0, xx1);
  __syncthreads();

  const float xxA = xxs[pa], xxB = xxs[pb];
  #pragma unroll
  for (int j = 0; j < 16; ++j) {      // in-place; m==p: (2X-X)-X == 0 exact
    float xm = xxs[j * 64 + lane];
    dotA[j] = (2.0f * dotA[j] - xxA) - xm;
    dotB[j] = (2.0f * dotB[j] - xxB) - xm;
  }
  select20f(dotA, lane, idx_out + ((long)b * NPTS + pa) * KK);
  select20f(dotB, lane, idx_out + ((long)b * NPTS + pb) * KK);
}

// ========== dual GEMV: Yc[b][n][o] = sum_c (w2-w1)*x,  G[b][m][o] = sum_c w1*x
template <typename AccT, int C, int O, int CB2, int TN>
__global__ __launch_bounds__(256) void cg_kernel(
    const float* __restrict__ x, long bstride,
    const float* __restrict__ W,
    AccT* __restrict__ Yc,
    AccT* __restrict__ G, long gbs)
{
  const int t = threadIdx.x, b = blockIdx.y;
  const int o = t & (O - 1);
  const int nbase = (t / O) * 16;
  const int nn0 = blockIdx.x * TN;
  __shared__ float s_wd[CB2 * O];
  __shared__ float s_w1[CB2 * O];
  __shared__ float s_xs[CB2 * TN];
  const float* xb = x + (long)b * bstride;

  AccT accC[16], accG[16];
  #pragma unroll
  for (int j = 0; j < 16; ++j) { accC[j] = (AccT)0; accG[j] = (AccT)0; }

  for (int c0 = 0; c0 < C; c0 += CB2) {
    __syncthreads();
    for (int i = t; i < CB2 * O; i += 256) {
      int oo = i / CB2, cc = i - oo * CB2;
      float a  = W[(long)oo * (2 * C) + c0 + cc];
      float b2 = W[(long)oo * (2 * C) + C + c0 + cc];
      s_wd[cc * O + oo] = b2 - a;
      s_w1[cc * O + oo] = a;
    }
    for (int i = t; i < CB2 * TN; i += 256) {
      int cc = i / TN, nn = i - cc * TN;
      s_xs[cc * TN + nn] = xb[(long)(c0 + cc) * NPTS + nn0 + nn];
    }
    __syncthreads();
    #pragma unroll
    for (int cc = 0; cc < CB2; ++cc) {
      float wd  = s_wd[cc * O + o];
      float w1v = s_w1[cc * O + o];
      #pragma unroll
      for (int j = 0; j < 16; ++j) {
        AccT xv = (AccT)s_xs[cc * TN + nbase + j];
        accC[j] += (AccT)wd  * xv;
        accG[j] += (AccT)w1v * xv;
      }
    }
  }
  #pragma unroll
  for (int j = 0; j < 16; ++j) {
    int n = nn0 + nbase + j;
    Yc[((long)b * NPTS + n) * O + o] = accC[j];
    G[(long)b * gbs + (long)n * O + o] = accG[j];
  }
}

// ============ EdgeConv epilogue: gather G rows, max/sum/sumsq over k ====
template <typename AccT, int O, int NPT, int ITERS>
__global__ __launch_bounds__(256) void ec_max_kernel(
    const int* __restrict__ idx,
    const AccT* __restrict__ G, long gbs,
    const AccT* __restrict__ Yc,
    double* __restrict__ sums,
    AccT* __restrict__ yraw)
{
  const int t = threadIdx.x, b = blockIdx.y;
  const int o = t & (O - 1);
  const int np = t / O;
  const int LP = NPT * ITERS;
  const int n0 = blockIdx.x * LP;

  __shared__ int s_jj[8 * KK];          // LP <= 8
  __shared__ double reds[256];
  __shared__ double redq[256];

  for (int i = t; i < LP * KK; i += 256) {
    int l = i / KK, kk = i - l * KK;
    s_jj[i] = idx[((long)b * NPTS + n0 + l) * KK + kk];
  }
  __syncthreads();

  const AccT* Gb = G + (long)b * gbs + o;
  double accS = 0.0, accQ = 0.0;
  #pragma unroll
  for (int it = 0; it < ITERS; ++it) {
    const int l = it * NPT + np;
    const int n = n0 + l;
    AccT y0 = Yc[((long)b * NPTS + n) * O + o];
    AccT ps = (AccT)0, pq = (AccT)0, pm = (AccT)(-INFINITY);
    #pragma unroll
    for (int k = 0; k < KK; ++k) {
      int j = s_jj[l * KK + k];          // wave-uniform (LDS broadcast)
      AccT v = Gb[(long)j * O] + y0;     // coalesced over o
      ps += v; pq += v * v;
      pm = (v > pm) ? v : pm;
    }
    yraw[((long)b * NPTS + n) * O + o] = pm;
    accS += (double)ps; accQ += (double)pq;
  }
  __syncthreads();
  reds[t] = accS; redq[t] = accQ;
  __syncthreads();
  if (t < O) {
    double s = 0.0, q = 0.0;
    #pragma unroll
    for (int g = 0; g < NPT; ++g) { s += reds[g * O + t]; q += redq[g * O + t]; }
    atomicAdd(&sums[t], s);
    atomicAdd(&sums[1024 + t], q);
  }
}

// normalize + lrelu the raw k-max, write into cat layout [b][o][n]
template <typename AccT, int O, int OL>
__global__ __launch_bounds__(256) void ec_norm(
    const AccT* __restrict__ yraw, const double* __restrict__ sums,
    const float* __restrict__ gamma, const float* __restrict__ beta,
    float* __restrict__ xout)
{
  int i = blockIdx.x * 256 + threadIdx.x;
  int n = i & (NPTS - 1);
  int o = (i >> 10) & (O - 1);
  int b = i >> (10 + OL);
  const double cnt = (double)BB * NPTS * KK;
  double m = sums[o] / cnt;
  double var = sums[1024 + o] / cnt - m * m;
  double inv = 1.0 / sqrt(var + (double)EPSF);
  AccT y = yraw[((long)b * NPTS + n) * O + o];
  AccT v = (y - (AccT)m) * (AccT)inv * (AccT)gamma[o] + (AccT)beta[o];
  v = (v >= (AccT)0) ? v : (AccT)0.2 * v;
  xout[(long)b * (512L * NPTS) + (long)o * NPTS + n] = (float)v;
}

// ============== Final 512->1024 conv, fused single pass =================
// v5 (R16, best measured): 256 o x 64 n, acc[4][16], grid (128,4), no
// atomics -- block partials to workspace, fin_reduce sums in fixed order.
#define WST2 260

__global__ __launch_bounds__(256, 2) void fin_fused(
    const float* __restrict__ cat, const float* __restrict__ W5,
    double* __restrict__ partS, float* __restrict__ partM)
{
  const int nt = blockIdx.x, ot = blockIdx.y, t = threadIdx.x;
  const int w = t >> 6, lane = t & 63;
  const int col0 = nt * 64;
  const int b = col0 >> 10;
  const int nb = col0 & 1023;

  __shared__ float sm[16 * WST2 + 16 * 64];   // 20.7 KB
  float* s_w = sm;             // [16][WST2]  (cc-major, +4 pad)
  float* s_f = sm + 16 * WST2; // [16][64]

  const int wrow0 = t >> 2, wcq = (t & 3) * 4;
  const float* wbase = W5 + ((long)(ot * 256 + wrow0)) * 512 + wcq;
  const int fcc = t >> 4, fnn = (t & 15) * 4;
  const float* fbase = cat + ((long)b * 512 + fcc) * 1024 + nb + fnn;

  float4 rw[4];
  float4 rf;
  #pragma unroll
  for (int q = 0; q < 4; ++q)
    rw[q] = *(const float4*)&wbase[(long)(64 * q) * 512];
  rf = *(const float4*)fbase;

  float acc[4][16];
  #pragma unroll
  for (int r = 0; r < 4; ++r)
    #pragma unroll
    for (int j = 0; j < 16; ++j) acc[r][j] = 0.f;

  for (int c0 = 0; c0 < 512; c0 += 16) {
    __syncthreads();                 // previous compute done reading LDS
    #pragma unroll
    for (int q = 0; q < 4; ++q) {
      float e[4] = {rw[q].x, rw[q].y, rw[q].z, rw[q].w};
      #pragma unroll
      for (int j = 0; j < 4; ++j)
        s_w[(wcq + j) * WST2 + wrow0 + 64 * q] = e[j];
    }
    *(float4*)&s_f[fcc * 64 + fnn] = rf;
    __syncthreads();
    if (c0 + 16 < 512) {             // prefetch next chunk -> overlaps compute
      #pragma unroll
      for (int q = 0; q < 4; ++q)
        rw[q] = *(const float4*)&wbase[(long)(64 * q) * 512 + c0 + 16];
      rf = *(const float4*)&fbase[(long)(c0 + 16) * 1024];
    }
    #pragma unroll
    for (int cc = 0; cc < 16; ++cc) {
      float4 wA = *(const float4*)&s_w[cc * WST2 + lane * 4];   // conflict-free
      float4 f0 = *(const float4*)&s_f[cc * 64 + w * 16];       // wave-uniform
      float4 f1 = *(const float4*)&s_f[cc * 64 + w * 16 + 4];   // broadcasts
      float4 f2 = *(const float4*)&s_f[cc * 64 + w * 16 + 8];
      float4 f3 = *(const float4*)&s_f[cc * 64 + w * 16 + 12];
      float wa[4] = {wA.x, wA.y, wA.z, wA.w};
      float fv[16] = {f0.x, f0.y, f0.z, f0.w, f1.x, f1.y, f1.z, f1.w,
                      f2.x, f2.y, f2.z, f2.w, f3.x, f3.y, f3.z, f3.w};
      #pragma unroll
      for (int r = 0; r < 4; ++r)
        #pragma unroll
        for (int j = 0; j < 16; ++j)
          acc[r][j] += wa[r] * fv[j];
    }
  }

  float psum[4], psq[4], pmx[4];
  #pragma unroll
  for (int r = 0; r < 4; ++r) {
    psum[r] = 0.f; psq[r] = 0.f; pmx[r] = -INFINITY;
    #pragma unroll
    for (int j = 0; j < 16; ++j) {
      float v = acc[r][j];
      psum[r] += v; psq[r] += v * v; pmx[r] = fmaxf(pmx[r], v);
    }
  }
  __syncthreads();
  float* red_s = sm;           // [4][256]
  float* red_q = sm + 1024;
  float* red_m = sm + 2048;
  #pragma unroll
  for (int r = 0; r < 4; ++r) {
    int oo = lane * 4 + r;
    red_s[w * 256 + oo] = psum[r];
    red_q[w * 256 + oo] = psq[r];
    red_m[w * 256 + oo] = pmx[r];
  }
  __syncthreads();
  {
    int oo = t;                // 0..255
    float s = 0.f, q = 0.f, m = -INFINITY;
    #pragma unroll
    for (int ww = 0; ww < 4; ++ww) {
      s += red_s[ww * 256 + oo];
      q += red_q[ww * 256 + oo];
      m = fmaxf(m, red_m[ww * 256 + oo]);
    }
    long base = (long)nt * 2048 + ot * 256 + oo;   // o = ot*256+oo
    partS[base]        = (double)s;                // coalesced, no atomics
    partS[base + 1024] = (double)q;
    partM[(long)nt * 1024 + ot * 256 + oo] = m;
  }
}

// sum the 128 nt-partials per (o, kind) slot in fixed ascending order
__global__ __launch_bounds__(256) void fin_reduce(
    const double* __restrict__ partS, double* __restrict__ sums)
{
  int slot = blockIdx.x * 256 + threadIdx.x;   // 0..2047
  double a = 0.0;
  for (int nt = 0; nt < 128; ++nt)
    a += partS[(long)nt * 2048 + slot];
  sums[slot] = a;
}

__global__ __launch_bounds__(256) void fin_norm(
    const float* __restrict__ partM, const double* __restrict__ sums,
    const float* __restrict__ g, const float* __restrict__ bt,
    float* __restrict__ out)
{
  int i = blockIdx.x * 256 + threadIdx.x;   // 8192
  int o = i & 1023;
  int b = i >> 10;
  double m = sums[o] / 8192.0;
  double var = sums[1024 + o] / 8192.0 - m * m;
  float inv = (float)(1.0 / sqrt(var + (double)EPSF));
  float y = -INFINITY;
  #pragma unroll 4
  for (int j = 0; j < 16; ++j)
    y = fmaxf(y, partM[(long)(b * 16 + j) * 1024 + o]);
  float v = (y - (float)m) * inv * g[o] + bt[o];
  out[i] = (v >= 0.f) ? v : 0.2f * v;
}

// ============================ launch ====================================
extern "C" void kernel_launch(void* const* d_in, const int* in_sizes, int n_in,
                              void* d_out, int out_size, void* d_ws, size_t ws_size,
                              hipStream_t stream)
{
  (void)in_sizes; (void)n_in; (void)out_size; (void)ws_size;
  const float* x0 = (const float*)d_in[0];
  const float* W1 = (const float*)d_in[1];
  const float* g1 = (const float*)d_in[2];
  const float* b1 = (const float*)d_in[3];
  const float* W2 = (const float*)d_in[4];
  const float* g2 = (const float*)d_in[5];
  const float* b2 = (const float*)d_in[6];
  const float* W3 = (const float*)d_in[7];
  const float* g3 = (const float*)d_in[8];
  const float* b3 = (const float*)d_in[9];
  const float* W4 = (const float*)d_in[10];
  const float* g4 = (const float*)d_in[11];
  const float* b4 = (const float*)d_in[12];
  const float* W5 = (const float*)d_in[13];
  const float* g5 = (const float*)d_in[14];
  const float* b5 = (const float*)d_in[15];
  float* outp = (float*)d_out;

  char* w = (char*)d_ws;
  double*   sums   = (double*)w;   w += 5 * 2048 * sizeof(double);            // 80 KB
  unsigned* mkeys  = (unsigned*)w; w += (size_t)BB * 1024 * sizeof(unsigned); // 32 KB (unused, layout kept)
  int*      idxbuf = (int*)w;      w += (size_t)BB * NPTS * KK * sizeof(int); // 640 KB
  char*     yraw   = w;            w += (size_t)BB * NPTS * 128 * sizeof(double); // 8 MB
  char*     ycbuf  = w;            w += (size_t)BB * NPTS * 128 * sizeof(double); // 8 MB
  float*    cat    = (float*)w;    // 16 MB

  double* sumsL[5] = {sums, sums + 2048, sums + 4096, sums + 6144, sums + 8192};

  const long catbs = 512L * NPTS;
  // G lives in the cat[256:512) slab per batch (1 MB/batch), which is only
  // written by layer-4's ec_norm -- strictly after every G consumer.
  float* gbase = cat + 256 * NPTS;
  // fin partials reuse yraw (dead after layer-4 ec_norm): 2 MB f64 + 0.5 MB f32
  double* partS = (double*)yraw;
  float*  partM = (float*)(yraw + (size_t)128 * 2048 * sizeof(double));

  dim3 gknn(NPTS / 16, BB);

  hipMemsetAsync(sums, 0, 5 * 2048 * sizeof(double) + (size_t)BB * 1024 * sizeof(unsigned),
                 stream);

  // ---- layer 1: x0 (C=3) -> cat[0:64), fp64 acc ----
  knn12_kernel<4, 3><<<gknn, 512, 0, stream>>>(x0, 3L * NPTS, idxbuf);
  cg_kernel<double, 3, 64, 3, 64><<<dim3(NPTS / 64, BB), 256, 0, stream>>>(
      x0, 3L * NPTS, W1, (double*)ycbuf, (double*)gbase, catbs / 2);
  ec_max_kernel<double, 64, 4, 2><<<dim3(NPTS / 8, BB), 256, 0, stream>>>(
      idxbuf, (const double*)gbase, catbs / 2, (const double*)ycbuf,
      sumsL[0], (double*)yraw);
  ec_norm<double, 64, 6><<<BB * 64 * NPTS / 256, 256, 0, stream>>>(
      (const double*)yraw, sumsL[0], g1, b1, cat);

  // ---- layer 2: cat[0:64) -> cat[64:128), fp64 acc ----
  knn12_kernel<64, 64><<<gknn, 512, 0, stream>>>(cat, catbs, idxbuf);
  cg_kernel<double, 64, 64, 16, 64><<<dim3(NPTS / 64, BB), 256, 0, stream>>>(
      cat, catbs, W2, (double*)ycbuf, (double*)gbase, catbs / 2);
  ec_max_kernel<double, 64, 4, 2><<<dim3(NPTS / 8, BB), 256, 0, stream>>>(
      idxbuf, (const double*)gbase, catbs / 2, (const double*)ycbuf,
      sumsL[1], (double*)yraw);
  ec_norm<double, 64, 6><<<BB * 64 * NPTS / 256, 256, 0, stream>>>(
      (const double*)yraw, sumsL[1], g2, b2, cat + 64 * NPTS);

  // ---- layer 3: cat[64:128) -> cat[128:256), fp64 acc ----
  knn12_kernel<64, 64><<<gknn, 512, 0, stream>>>(cat + 64 * NPTS, catbs, idxbuf);
  cg_kernel<double, 64, 128, 16, 32><<<dim3(NPTS / 32, BB), 256, 0, stream>>>(
      cat + 64 * NPTS, catbs, W3, (double*)ycbuf, (double*)gbase, catbs / 2);
  ec_max_kernel<double, 128, 2, 4><<<dim3(NPTS / 8, BB), 256, 0, stream>>>(
      idxbuf, (const double*)gbase, catbs / 2, (const double*)ycbuf,
      sumsL[2], (double*)yraw);
  ec_norm<double, 128, 7><<<BB * 128 * NPTS / 256, 256, 0, stream>>>(
      (const double*)yraw, sumsL[2], g3, b3, cat + 128 * NPTS);

  // ---- layer 4: cat[128:256) -> cat[256:512), fp32 acc (continuous path) ----
  knn12_kernel<128, 128><<<gknn, 512, 0, stream>>>(cat + 128 * NPTS, catbs, idxbuf);
  cg_kernel<float, 128, 256, 16, 16><<<dim3(NPTS / 16, BB), 256, 0, stream>>>(
      cat + 128 * NPTS, catbs, W4, (float*)ycbuf, gbase, catbs);
  ec_max_kernel<float, 256, 1, 4><<<dim3(NPTS / 4, BB), 256, 0, stream>>>(
      idxbuf, (const float*)gbase, catbs, (const float*)ycbuf,
      sumsL[3], (float*)yraw);
  ec_norm<float, 256, 8><<<BB * 256 * NPTS / 256, 256, 0, stream>>>(
      (const float*)yraw, sumsL[3], g4, b4, cat + 256 * NPTS);

  // ---- final 512->1024 conv + BN + lrelu + max over n (no atomics) ----
  dim3 gf(128, 4);
  fin_fused<<<gf, 256, 0, stream>>>(cat, W5, partS, partM);
  fin_reduce<<<8, 256, 0, stream>>>(partS, sumsL[4]);
  fin_norm<<<BB * 1024 / 256, 256, 0, stream>>>(partM, sumsL[4], g5, b5, outp);
}